// Round 5
// baseline (739.919 us; speedup 1.0000x reference)
//
#include <hip/hip_runtime.h>

#define K_DIM   4096
#define N_DIM   4096
#define M_ROWS  8192
#define KF      (K_DIM / 4)    // 1024 float4 per x/A row
#define NF      (N_DIM / 4)    // 1024 float4 per out/Bt row
#define KSPLIT  2
#define NTILES  (M_ROWS / 16)  // 512 row tiles

// d_ws layout (floats unless noted):
//   Bt    [16][4096]          offset 0        (65536 floats, 256 KB)
//   tpart [2][8192][16]       offset 65536    (262144 floats, 1 MB)
//   cnt   [512] (int)         offset 65536+262144

// ---------------------------------------------------------------------------
// Prep: transpose B [4096][16] -> Bt [16][4096], and zero election counters.
__global__ __launch_bounds__(256) void lora_prep(const float* __restrict__ B,
                                                 float* __restrict__ Bt,
                                                 int* __restrict__ cnt) {
    if (blockIdx.x < 256) {
        const int i = blockIdx.x * 256 + threadIdx.x;   // 0 .. 65535
        const int r = i >> 12;                          // 0..15
        const int c = i & (N_DIM - 1);                  // 0..4095
        Bt[i] = B[c * 16 + r];
    } else {
        cnt[threadIdx.x] = 0;
        cnt[threadIdx.x + 256] = 0;
    }
}

// ---------------------------------------------------------------------------
// Fused producer/consumer with election.
// Grid: NTILES * KSPLIT blocks of 256 threads (4 waves x 4 rows = 16 rows).
// Phase 1: partial t over this block's K-half (lanes along K, 1KB bursts),
//          in-wave butterfly, 256B/wave partial store.
// Election: last block of the tile (atomicAdd) sums partials in FIXED order
//          and runs phase 2 for the whole 16x4096 output tile.
__global__ __launch_bounds__(256, 4) void lora_fused(const float* __restrict__ x,
                                                     const float* __restrict__ A,
                                                     const float* __restrict__ Bt,
                                                     float* __restrict__ tpart,
                                                     int* __restrict__ cnt,
                                                     float* __restrict__ out) {
    __shared__ float t_s[256];
    __shared__ int elect_s;

    const int tid  = threadIdx.x;
    const int wv   = tid >> 6;
    const int lane = tid & 63;
    const int rb   = blockIdx.x >> 1;     // row tile 0..511
    const int h    = blockIdx.x & 1;      // K half
    const int row0 = rb * 16 + wv * 4;
    const int kbase = h * 512;            // float4 units (1024/2)

    const float4* x4 = (const float4*)x;
    const float4* A4 = (const float4*)A;

    // ---- phase 1: acc[j*16+r] over this lane's k slice ----
    float red[64];
    #pragma unroll
    for (int v = 0; v < 64; ++v) red[v] = 0.f;

    for (int it = 0; it < 8; ++it) {
        const int kf = kbase + it * 64 + lane;
        float4 xv[4];
        #pragma unroll
        for (int j = 0; j < 4; ++j)
            xv[j] = x4[(size_t)(row0 + j) * KF + kf];
        #pragma unroll
        for (int r = 0; r < 16; ++r) {
            const float4 av = A4[r * KF + kf];
            #pragma unroll
            for (int j = 0; j < 4; ++j) {
                float a = red[j * 16 + r];
                a = fmaf(xv[j].x, av.x, a);
                a = fmaf(xv[j].y, av.y, a);
                a = fmaf(xv[j].z, av.z, a);
                a = fmaf(xv[j].w, av.w, a);
                red[j * 16 + r] = a;
            }
        }
    }

    // ---- in-wave butterfly: lane l ends with sum over lanes of red[l] ----
    #pragma unroll
    for (int s = 0; s < 6; ++s) {
        const int m = 1 << s;
        const int b = (lane >> s) & 1;
        #pragma unroll
        for (int u = 0; u < (64 >> (s + 1)); ++u) {
            const float lo = red[2 * u];
            const float hi = red[2 * u + 1];
            const float send = b ? lo : hi;
            const float recv = __shfl_xor(send, m, 64);
            const float kept = b ? hi : lo;
            red[u] = kept + recv;
        }
    }

    // partial store: tpart[h][row0 + (lane>>4)][lane&15]  (256B per wave)
    tpart[((size_t)h * M_ROWS + row0) * 16 + lane] = red[0];
    __threadfence();                       // release our partial
    __syncthreads();

    if (tid == 0) {
        const int old = atomicAdd(&cnt[rb], 1);
        elect_s = (old == KSPLIT - 1);
    }
    __syncthreads();
    if (!elect_s) return;

    // ---- elected: acquire, sum partials in fixed order, run phase 2 ----
    __threadfence();
    {
        const float v0 = tpart[(size_t)rb * 256 + tid];
        const float v1 = tpart[(size_t)M_ROWS * 16 + rb * 256 + tid];
        t_s[tid] = v0 + v1;                // t[rb*16 + tid>>4][tid&15]
    }
    __syncthreads();

    const float4* Bt4 = (const float4*)Bt;
    const float4* ts4 = (const float4*)t_s;
    float4* out4 = (float4*)out;

    for (int cb = 0; cb < 4; ++cb) {
        const int c4 = cb * 256 + tid;     // float4 column index
        float4 bv[16];
        #pragma unroll
        for (int r = 0; r < 16; ++r)
            bv[r] = Bt4[r * NF + c4];      // 1KB burst, L2-hot
        #pragma unroll
        for (int row = 0; row < 16; ++row) {
            float4 tq[4];
            #pragma unroll
            for (int q = 0; q < 4; ++q)
                tq[q] = ts4[row * 4 + q];  // LDS broadcast
            float4 o = {0.f, 0.f, 0.f, 0.f};
            #pragma unroll
            for (int r = 0; r < 16; ++r) {
                const float4 tv4 = tq[r >> 2];
                const float tv = ((r & 3) == 0) ? tv4.x :
                                 ((r & 3) == 1) ? tv4.y :
                                 ((r & 3) == 2) ? tv4.z : tv4.w;
                o.x = fmaf(tv, bv[r].x, o.x);
                o.y = fmaf(tv, bv[r].y, o.y);
                o.z = fmaf(tv, bv[r].z, o.z);
                o.w = fmaf(tv, bv[r].w, o.w);
            }
            out4[(size_t)(rb * 16 + row) * NF + c4] = o;
        }
    }
}

extern "C" void kernel_launch(void* const* d_in, const int* in_sizes, int n_in,
                              void* d_out, int out_size, void* d_ws, size_t ws_size,
                              hipStream_t stream) {
    const float* x = (const float*)d_in[0];            // [4,2048,4096]
    const float* B = (const float*)d_in[1];            // [4096,16]
    const float* A = (const float*)d_in[2];            // [16,4096]
    float* out = (float*)d_out;                        // [4,2048,4096]

    float* Bt    = (float*)d_ws;                       // 65536 floats
    float* tpart = Bt + 16 * N_DIM;                    // 262144 floats
    int*   cnt   = (int*)(tpart + KSPLIT * M_ROWS * 16);

    lora_prep<<<257, 256, 0, stream>>>(B, Bt, cnt);
    lora_fused<<<NTILES * KSPLIT, 256, 0, stream>>>(x, A, Bt, tpart, cnt, out);
}

// Round 7
// 66.069 us; speedup vs baseline: 11.1991x; 11.1991x over previous
//
#include <hip/hip_runtime.h>

#define K_DIM   4096
#define N_DIM   4096
#define M_ROWS  8192
#define KF      (K_DIM / 4)      // 1024 float4 per x/A row
#define NF      (N_DIM / 4)      // 1024 float4 per out row
#define KSPLIT  8
#define KCH     (KF / KSPLIT)    // 128 float4 per K-chunk
#define NTILES  (M_ROWS / 16)    // 512 row tiles
#define TP_F4_STRIDE (M_ROWS * 16 / 4)   // 32768 float4 per k-partial slab

// ---------------------------------------------------------------------------
// Kernel 1: t partials. Grid = NTILES*KSPLIT blocks, 256 thr (4 waves x 4 rows).
// A-chunk (16 x 128 float4 = 32 KB) staged in LDS once per block, so the
// global stream is almost pure x (1KB bursts, lanes along K).
// In-wave butterfly -> lane l holds partial t[row0+(l>>4)][l&15].
__global__ __launch_bounds__(256, 4) void lora_xat(const float* __restrict__ x,
                                                   const float* __restrict__ A,
                                                   float* __restrict__ tpart) {
    __shared__ float4 Alds[16 * KCH];     // 32 KB

    const int tid  = threadIdx.x;
    const int wv   = tid >> 6;            // wave -> 4-row group
    const int lane = tid & 63;
    const int rb   = blockIdx.x >> 3;     // 16-row tile
    const int h    = blockIdx.x & 7;      // K eighth
    const int row0 = rb * 16 + wv * 4;
    const int kbase = h * KCH;            // float4 units

    const float4* x4 = (const float4*)x;
    const float4* A4 = (const float4*)A;

    // stage A chunk: idx = r*128 + c, coalesced 2KB per half-wave
    #pragma unroll
    for (int i = 0; i < 8; ++i) {
        const int idx = i * 256 + tid;    // 0..2047
        const int r = idx >> 7;
        const int c = idx & (KCH - 1);
        Alds[idx] = A4[r * KF + kbase + c];
    }

    float red[64];
    #pragma unroll
    for (int v = 0; v < 64; ++v) red[v] = 0.f;

    __syncthreads();

    #pragma unroll
    for (int it = 0; it < 2; ++it) {
        const int kl = it * 64 + lane;    // 0..127 within chunk
        const int kf = kbase + kl;
        float4 xv[4];
        #pragma unroll
        for (int j = 0; j < 4; ++j)
            xv[j] = x4[(size_t)(row0 + j) * KF + kf];
        #pragma unroll
        for (int r = 0; r < 16; ++r) {
            const float4 av = Alds[r * KCH + kl];   // conflict-free b128
            #pragma unroll
            for (int j = 0; j < 4; ++j) {
                float a = red[j * 16 + r];
                a = fmaf(xv[j].x, av.x, a);
                a = fmaf(xv[j].y, av.y, a);
                a = fmaf(xv[j].z, av.z, a);
                a = fmaf(xv[j].w, av.w, a);
                red[j * 16 + r] = a;
            }
        }
    }

    // in-wave butterfly: lane l ends with sum over lanes of red[l]
    #pragma unroll
    for (int s = 0; s < 6; ++s) {
        const int m = 1 << s;
        const int b = (lane >> s) & 1;
        #pragma unroll
        for (int u = 0; u < (64 >> (s + 1)); ++u) {
            const float lo = red[2 * u];
            const float hi = red[2 * u + 1];
            const float send = b ? lo : hi;
            const float recv = __shfl_xor(send, m, 64);
            const float kept = b ? hi : lo;
            red[u] = kept + recv;
        }
    }

    // contiguous 256B store per wave: tpart[h][row0 + (lane>>4)][lane&15]
    tpart[((size_t)h * M_ROWS + row0) * 16 + lane] = red[0];
}

// ---------------------------------------------------------------------------
// Kernel 2: out = t @ B^T. Block = 16 rows x 1024 cols, 256 threads.
// Thread owns 4 consecutive output cols; B values for those cols live in
// registers (contiguous 256B per thread, L1/L2-hot). tpart summed by all
// 256 threads, then broadcast from 1 KB LDS. Stores: 1KB coalesced bursts.
__global__ __launch_bounds__(256, 4) void lora_tb(const float* __restrict__ tpart,
                                                  const float* __restrict__ B,
                                                  float* __restrict__ out) {
    __shared__ float4 tp_s[4][64];
    __shared__ float4 t_s4[64];           // 16 rows x 16 r

    const int tid = threadIdx.x;
    const int rb  = blockIdx.x >> 2;      // 16-row tile
    const int cb  = blockIdx.x & 3;       // 1024-col chunk

    // B into registers: 4 cols x 16 r = 256B contiguous per thread
    const int o0 = cb * 1024 + tid * 4;   // first of 4 output cols
    float4 breg[4][4];
    const float4* B4 = (const float4*)B;
    #pragma unroll
    for (int j = 0; j < 4; ++j)
        #pragma unroll
        for (int q = 0; q < 4; ++q)
            breg[j][q] = B4[(size_t)(o0 + j) * 4 + q];

    // parallel tpart sum: 8 slabs -> 4 partials -> 1
    {
        const int f  = tid & 63;
        const int hp = tid >> 6;          // 0..3
        const float4* p4 = (const float4*)tpart;
        float4 a = p4[(size_t)(2 * hp) * TP_F4_STRIDE + rb * 64 + f];
        const float4 b = p4[(size_t)(2 * hp + 1) * TP_F4_STRIDE + rb * 64 + f];
        a.x += b.x; a.y += b.y; a.z += b.z; a.w += b.w;
        tp_s[hp][f] = a;
    }
    __syncthreads();
    if (tid < 64) {
        float4 s = tp_s[0][tid];
        #pragma unroll
        for (int hp = 1; hp < 4; ++hp) {
            const float4 q = tp_s[hp][tid];
            s.x += q.x; s.y += q.y; s.z += q.z; s.w += q.w;
        }
        t_s4[tid] = s;                    // t[rb*16 + tid>>2... ] row*4+q layout
    }
    __syncthreads();

    float4* out4 = (float4*)out;
    const int c4 = cb * 256 + tid;        // float4 column index

    #pragma unroll
    for (int row = 0; row < 16; ++row) {
        float4 tq[4];
        #pragma unroll
        for (int q = 0; q < 4; ++q)
            tq[q] = t_s4[row * 4 + q];    // LDS broadcast (same addr all lanes)
        float o0v = 0.f, o1v = 0.f, o2v = 0.f, o3v = 0.f;
        #pragma unroll
        for (int r = 0; r < 16; ++r) {
            const float4 tv4 = tq[r >> 2];
            const float tv = ((r & 3) == 0) ? tv4.x :
                             ((r & 3) == 1) ? tv4.y :
                             ((r & 3) == 2) ? tv4.z : tv4.w;
            o0v = fmaf(tv, ((const float*)&breg[0][0])[r], o0v);
            o1v = fmaf(tv, ((const float*)&breg[1][0])[r], o1v);
            o2v = fmaf(tv, ((const float*)&breg[2][0])[r], o2v);
            o3v = fmaf(tv, ((const float*)&breg[3][0])[r], o3v);
        }
        const float4 o = {o0v, o1v, o2v, o3v};
        out4[(size_t)(rb * 16 + row) * NF + c4] = o;
    }
}

extern "C" void kernel_launch(void* const* d_in, const int* in_sizes, int n_in,
                              void* d_out, int out_size, void* d_ws, size_t ws_size,
                              hipStream_t stream) {
    const float* x = (const float*)d_in[0];            // [4,2048,4096]
    const float* B = (const float*)d_in[1];            // [4096,16]
    const float* A = (const float*)d_in[2];            // [16,4096]
    float* out = (float*)d_out;                        // [4,2048,4096]

    float* tpart = (float*)d_ws;                       // [8][8192][16], 4 MB

    lora_xat<<<NTILES * KSPLIT, 256, 0, stream>>>(x, A, tpart);
    lora_tb<<<NTILES * (N_DIM / 1024), 256, 0, stream>>>(tpart, B, out);
}